// Round 9
// baseline (187.483 us; speedup 1.0000x reference)
//
#include <hip/hip_runtime.h>
#include <stdint.h>

#define TOKENS 8192
#define IN_F   4096
#define OUT_F  4096

#define BM 256
#define BN 256
#define BK 64                 // bytes of K per slice (64 int8)
#define NK (IN_F / BK)        // 64 slices
#define THREADS 1024

typedef int v4i __attribute__((ext_vector_type(4)));

#define GLOBAL_AS __attribute__((address_space(1)))
#define LDS_AS    __attribute__((address_space(3)))

// ---------------- pack x: int32 -> int8 ----------------
__global__ __launch_bounds__(256) void pack_x_kernel(const int* __restrict__ x32,
                                                     uint8_t* __restrict__ x8) {
  int t = blockIdx.x * 256 + threadIdx.x;
  const int4 v = ((const int4*)x32)[t];
  uint32_t p = (uint32_t)(v.x & 0xFF)
             | ((uint32_t)(v.y & 0xFF) << 8)
             | ((uint32_t)(v.z & 0xFF) << 16)
             | ((uint32_t)(v.w & 0xFF) << 24);
  ((uint32_t*)x8)[t] = p;
}

// -------- pack + transpose W: int32 [K][N] -> int8 WT [N][K] --------
__global__ __launch_bounds__(256) void packT_w_kernel(const int* __restrict__ w32,
                                                      uint8_t* __restrict__ wt8) {
  int tn = (blockIdx.x & 63) * 64;
  int tk = (blockIdx.x >> 6) * 64;
  int t = threadIdx.x;
  int n  = tn + (t >> 2);
  int k0 = tk + (t & 3) * 16;
  uint32_t words[4];
#pragma unroll
  for (int w = 0; w < 4; ++w) {
    uint32_t acc = 0;
#pragma unroll
    for (int j = 0; j < 4; ++j) {
      int val = w32[(size_t)(k0 + w * 4 + j) * OUT_F + n];
      acc |= (uint32_t)(val & 0xFF) << (8 * j);
    }
    words[w] = acc;
  }
  uint4 o = make_uint4(words[0], words[1], words[2], words[3]);
  *(uint4*)(wt8 + (size_t)n * IN_F + k0) = o;
}

// ---------------- int8 GEMM: 256x256, 16 waves, ring-4, 4 waves/SIMD ----------------
// 16 waves (4m x 4n), wave tile 64x64, 4x4 frags of mfma_i32_16x16x64_i8 (acc 64 reg).
// R9 change vs R8: no lgkmcnt(0)/sched_barrier pin before the MFMA cluster --
// compiler emits counted lgkmcnt so MFMAs interleave with draining ds_reads.
// Cross-wave hazard proof unchanged: every wave's slot-(i-1) reads are consumed
// by its slice-(i-1) MFMAs (compiler-forced lgkm drain) before it reaches iter
// i's barrier; stage(i+3) (slot (i-1)&3) issues only after that barrier.
__global__ __launch_bounds__(THREADS, 4) void gemm_i8_kernel(const uint8_t* __restrict__ A,
                                                             const uint8_t* __restrict__ BT,
                                                             const int* __restrict__ bias,
                                                             const float* __restrict__ scales,
                                                             int* __restrict__ out) {
  __shared__ __align__(16) uint8_t lds[4 * 32768];   // ring of 4 slices, 128 KiB

  const int t    = threadIdx.x;
  const int lane = t & 63;
  const int w    = t >> 6;     // 0..15
  const int wm   = w >> 2;     // 0..3
  const int wn   = w & 3;      // 0..3
  const int fr   = lane & 15;
  const int fq   = lane >> 4;

  // XCD-aware bijective swizzle: 512 blocks, 512 % 8 == 0
  int bid = blockIdx.x;
  int swz = (bid & 7) * 64 + (bid >> 3);
  int bm = swz >> 4;           // 0..31
  int bn = swz & 15;           // 0..15

  // staging: pre-swizzled global source, linear LDS dest (rule #21).
  // Per-half (128 rows x 64 B = 8 KiB) sigma layout verified 0-conflict R3-R8.
  const int half = t >> 9;              // 0..1
  const int tt   = t & 511;
  const int lsz  = tt ^ ((tt >> 3) & 7);
  const int srow = half * 128 + (lsz >> 2);   // 0..255
  const int scol = (lsz & 3) * 16;
  const size_t gA = (size_t)(bm * BM + srow) * IN_F + scol;
  const size_t gB = (size_t)(bn * BN + srow) * IN_F + scol;
  const int ldst = half * 8192 + tt * 16;

  auto stage = [&](int j) {            // 2 loads per thread per slice
    uint8_t* sb = lds + (j & 3) * 32768;
    const int k0 = j * BK;
    __builtin_amdgcn_global_load_lds((const GLOBAL_AS void*)(A + gA + k0),
                                     (LDS_AS void*)(sb + ldst),          16, 0, 0);
    __builtin_amdgcn_global_load_lds((const GLOBAL_AS void*)(BT + gB + k0),
                                     (LDS_AS void*)(sb + 16384 + ldst),  16, 0, 0);
  };

  // fragment read offsets (slot-relative), sigma-swizzled to match staging
  int aoff[4], boff[4];
#pragma unroll
  for (int m = 0; m < 4; ++m) {
    int row = wm * 64 + m * 16 + fr;        // 0..255
    int hh = row >> 7, rl = row & 127;
    int b = rl * 64 + fq * 16;
    b ^= ((rl >> 1) & 7) << 4;
    aoff[m] = hh * 8192 + b;
  }
#pragma unroll
  for (int n = 0; n < 4; ++n) {
    int row = wn * 64 + n * 16 + fr;        // 0..255
    int hh = row >> 7, rl = row & 127;
    int b = rl * 64 + fq * 16;
    b ^= ((rl >> 1) & 7) << 4;
    boff[n] = 16384 + hh * 8192 + b;
  }

  v4i acc[4][4];
  const v4i vzero = {0, 0, 0, 0};
#pragma unroll
  for (int m = 0; m < 4; ++m)
#pragma unroll
    for (int n = 0; n < 4; ++n) acc[m][n] = vzero;

  // Prologue: fill 3 slots (6 loads/thread in flight).
  stage(0); stage(1); stage(2);

  // ITER(i): vmcnt(VM) -> slice i landed; barrier; stage(i+3); ds_read 8x b128;
  // MFMAs with compiler-counted lgkm waits (no full drain, no sched pin).
#define ITER(i, VM, DOSTAGE)                                                    \
  {                                                                             \
    asm volatile("s_waitcnt vmcnt(" #VM ")" ::: "memory");                      \
    asm volatile("s_barrier" ::: "memory");                                     \
    if (DOSTAGE) stage((i) + 3);                                                \
    const uint8_t* sb = lds + ((i) & 3) * 32768;                                \
    v4i af[4], bf[4];                                                           \
    _Pragma("unroll") for (int m = 0; m < 4; ++m)                               \
      af[m] = *(const v4i*)(sb + aoff[m]);                                      \
    _Pragma("unroll") for (int n = 0; n < 4; ++n)                               \
      bf[n] = *(const v4i*)(sb + boff[n]);                                      \
    __builtin_amdgcn_s_setprio(1);                                              \
    _Pragma("unroll") for (int m = 0; m < 4; ++m)                               \
      _Pragma("unroll") for (int n = 0; n < 4; ++n)                             \
        acc[m][n] = __builtin_amdgcn_mfma_i32_16x16x64_i8(af[m], bf[n],         \
                                                          acc[m][n], 0, 0, 0);  \
    __builtin_amdgcn_s_setprio(0);                                              \
  }

  for (int i = 0; i < NK - 3; ++i) {
    ITER(i, 4, true)
  }
  ITER(NK - 3, 4, false)
  ITER(NK - 2, 2, false)
  ITER(NK - 1, 0, false)
#undef ITER

  // ---- epilogue: (acc + bias) * scale * 20, clip, trunc; int32 out ----
  // C/D layout (16x16): col = lane&15, row = (lane>>4)*4 + r
#pragma unroll
  for (int n = 0; n < 4; ++n) {
    const int gn  = bn * BN + wn * 64 + n * 16 + fr;
    const int bsv = bias[gn];
    const float sc = scales[gn] * 20.0f;
#pragma unroll
    for (int m = 0; m < 4; ++m) {
      const int gm0 = bm * BM + wm * 64 + m * 16 + fq * 4;
#pragma unroll
      for (int r = 0; r < 4; ++r) {
        float g = (float)(acc[m][n][r] + bsv) * sc;
        g = fminf(fmaxf(g, -128.0f), 127.0f);
        out[(size_t)(gm0 + r) * OUT_F + gn] = (int)g;
      }
    }
  }
}

extern "C" void kernel_launch(void* const* d_in, const int* in_sizes, int n_in,
                              void* d_out, int out_size, void* d_ws, size_t ws_size,
                              hipStream_t stream) {
  const int*   x32    = (const int*)d_in[0];
  const int*   w32    = (const int*)d_in[1];
  const int*   bias   = (const int*)d_in[2];
  const float* scales = (const float*)d_in[3];
  int* out = (int*)d_out;

  uint8_t* x8  = (uint8_t*)d_ws;                              // 32 MB
  uint8_t* wt8 = (uint8_t*)d_ws + (size_t)TOKENS * IN_F;      // 16 MB

  pack_x_kernel<<<(TOKENS * IN_F / 4) / 256, 256, 0, stream>>>(x32, x8);
  packT_w_kernel<<<(OUT_F / 64) * (IN_F / 64), 256, 0, stream>>>(w32, wt8);
  gemm_i8_kernel<<<(TOKENS / BM) * (OUT_F / BN), THREADS, 0, stream>>>(x8, wt8, bias, scales, out);
}